// Round 1
// baseline (887.876 us; speedup 1.0000x reference)
//
#include <hip/hip_runtime.h>
#include <hip/hip_bf16.h>

// Shapes: N=128, C_IN=C_OUT=64, T=128, V=25, S=3, R=8
// ws layout (floats):
//   adj   [3][128][64][625] @ 0          (15,360,000)
//   xbar  [128][64][25]     @ 15,360,000 (204,800)
//   stats [64][2]           @ 15,564,800 (128)
//   coef  [64][2]           @ 15,564,928 (128)

#define ADJ_OFF   0
#define XBAR_OFF  15360000
#define STATS_OFF 15564800
#define COEF_OFF  15564928

__global__ void k_zero(float* stats) {
    if (threadIdx.x < 128) stats[threadIdx.x] = 0.f;
}

// K1: xbar[n,c,v] = mean over t of x[n,c,t,v]. One wave per (n,c).
__global__ void k_xbar(const float* __restrict__ x, float* __restrict__ xbar) {
    int nc = blockIdx.x;          // 0..8191
    int lane = threadIdx.x;       // 64 threads
    const float* p = x + (long)nc * 3200;
    float acc[25];
#pragma unroll
    for (int v = 0; v < 25; v++) acc[v] = 0.f;
    for (int t = lane; t < 128; t += 64) {
        const float* q = p + t * 25;
#pragma unroll
        for (int v = 0; v < 25; v++) acc[v] += q[v];
    }
#pragma unroll
    for (int v = 0; v < 25; v++) {
        float a = acc[v];
        for (int off = 32; off; off >>= 1) a += __shfl_down(a, off);
        if (lane == 0) xbar[nc * 25 + v] = a * (1.f / 128.f);
    }
}

// K2: adj[s,n,o,u,v] = alpha*(sum_r W4[o,r]*tanh(x1[r,u]-x2[r,v]) + b4[o]) + PA[u,v]
__global__ void k_adj(const float* __restrict__ xbar,
                      const float* __restrict__ W1, const float* __restrict__ b1,
                      const float* __restrict__ W2, const float* __restrict__ b2,
                      const float* __restrict__ W4, const float* __restrict__ b4,
                      const float* __restrict__ PA, const float* __restrict__ alpha,
                      float* __restrict__ adj_ws) {
    int sb = blockIdx.x;          // 0..383
    int s = sb >> 7, n = sb & 127;
    __shared__ float xb[1600];
    __shared__ float x1l[8][25], x2l[8][25];
    __shared__ float w1l[512], w2l[512], w4l[512];
    __shared__ float b4l[64];
    int tid = threadIdx.x;        // 256
    for (int i = tid; i < 1600; i += 256) xb[i] = xbar[n * 1600 + i];
    for (int i = tid; i < 512; i += 256) {
        w1l[i] = W1[s * 512 + i];
        w2l[i] = W2[s * 512 + i];
        w4l[i] = W4[s * 512 + i];
    }
    if (tid < 64) b4l[tid] = b4[s * 64 + tid];
    __syncthreads();
    if (tid < 200) {
        int r = tid / 25, v = tid % 25;
        float a1 = b1[s * 8 + r], a2 = b2[s * 8 + r];
        for (int c = 0; c < 64; c++) {
            float xv = xb[c * 25 + v];
            a1 += w1l[r * 64 + c] * xv;
            a2 += w2l[r * 64 + c] * xv;
        }
        x1l[r][v] = a1;
        x2l[r][v] = a2;
    }
    __syncthreads();
    float al = alpha[s];
    for (int p = tid; p < 625; p += 256) {
        int u = p / 25, v = p % 25;
        float d8[8];
#pragma unroll
        for (int r = 0; r < 8; r++) d8[r] = tanhf(x1l[r][u] - x2l[r][v]);
        float pa = PA[s * 625 + p];
        long base = ((long)(s * 128 + n) * 64) * 625 + p;
        for (int o = 0; o < 64; o++) {
            float acc = b4l[o];
#pragma unroll
            for (int r = 0; r < 8; r++) acc += w4l[o * 8 + r] * d8[r];
            adj_ws[base + (long)o * 625] = acc * al + pa;
        }
    }
}

// K3: y[n,o,t,u] = sum_s sum_v adj[s,n,o,u,v] * (sum_c W3[s,o,c] x[n,c,t,v] + b3[s,o])
// block = (n, o-tile of 8), 512 threads, Tt=8 staged in LDS.
__launch_bounds__(512, 1)
__global__ void k_main(const float* __restrict__ x, const float* __restrict__ W3,
                       const float* __restrict__ b3, const float* __restrict__ adj_ws,
                       float* __restrict__ y) {
    __shared__ float xl[64 * 200];          // 51200 B
    __shared__ float adjl[3 * 8 * 25 * 28]; // 67200 B  (rows padded 25->28 for float4)
    __shared__ float w3l[3 * 64 * 8];       // [s][c][o8] transposed, 6144 B
    __shared__ float b3l[24];
    __shared__ float x3l[8 * 8 * 28];       // [o8][t][v pad 28], 7168 B

    int bid = blockIdx.x;                   // 0..1023
    int xcd = bid & 7, j = bid >> 3;
    int ot = j & 7, n = (xcd << 4) | (j >> 3);   // same-n blocks -> same XCD
    int o0 = ot * 8;
    int tid = threadIdx.x;

    for (int i = tid; i < 1536; i += 512) {
        int s = i >> 9, rem = i & 511, o8 = rem >> 6, c = rem & 63;
        w3l[s * 512 + c * 8 + o8] = W3[(s * 64 + o0 + o8) * 64 + c];
    }
    if (tid < 24) {
        int s = tid / 8, o8 = tid % 8;
        b3l[tid] = b3[s * 64 + o0 + o8];
    }
    for (int i = tid; i < 15000; i += 512) {
        int s = i / 5000, rem = i % 5000;
        int o8 = rem / 625, p = rem % 625;
        int u = p / 25, v = p % 25;
        adjl[((s * 8 + o8) * 25 + u) * 28 + v] =
            adj_ws[((long)((s * 128 + n) * 64 + o0 + o8)) * 625 + p];
    }
    __syncthreads();

    int grp = tid >> 8;          // 0/1 -> o8 range grp*4..grp*4+3
    int e = tid & 255;
    int t_ = e / 25, u_ = e % 25;
    bool act = e < 200;
    const float* xn = x + (long)n * 64 * 3200;

    for (int tt = 0; tt < 16; tt++) {
        for (int i = tid; i < 12800; i += 512) {
            int c = i / 200, ee = i % 200;
            xl[c * 200 + ee] = xn[c * 3200 + tt * 200 + ee];
        }
        __syncthreads();
        float y0 = 0, y1 = 0, y2 = 0, y3 = 0;
        for (int s = 0; s < 3; s++) {
            // phase A: x3 for 4 o's per thread
            if (act) {
                float a0 = 0, a1 = 0, a2 = 0, a3 = 0;
                const float* wp = &w3l[s * 512 + grp * 4];
#pragma unroll
                for (int c = 0; c < 64; c++) {
                    float xv = xl[c * 200 + e];
                    float4 w = *(const float4*)(wp + c * 8);
                    a0 += w.x * xv; a1 += w.y * xv; a2 += w.z * xv; a3 += w.w * xv;
                }
                const float* bp = &b3l[s * 8 + grp * 4];
                a0 += bp[0]; a1 += bp[1]; a2 += bp[2]; a3 += bp[3];
                int ob = grp * 4;
                x3l[(ob + 0) * 224 + t_ * 28 + u_] = a0;
                x3l[(ob + 1) * 224 + t_ * 28 + u_] = a1;
                x3l[(ob + 2) * 224 + t_ * 28 + u_] = a2;
                x3l[(ob + 3) * 224 + t_ * 28 + u_] = a3;
            }
            __syncthreads();
            // phase B: y[t,u] += sum_v adj[u,v] * x3[t,v]
            if (act) {
#pragma unroll
                for (int k = 0; k < 4; k++) {
                    int o8 = grp * 4 + k;
                    const float* ar = &adjl[((s * 8 + o8) * 25 + u_) * 28];
                    const float* xr = &x3l[o8 * 224 + t_ * 28];
                    float acc = 0.f;
#pragma unroll
                    for (int vb = 0; vb < 6; vb++) {
                        float4 a = *(const float4*)(ar + vb * 4);
                        float4 xv = *(const float4*)(xr + vb * 4);
                        acc += a.x * xv.x + a.y * xv.y + a.z * xv.z + a.w * xv.w;
                    }
                    acc += ar[24] * xr[24];
                    if (k == 0) y0 += acc; else if (k == 1) y1 += acc;
                    else if (k == 2) y2 += acc; else y3 += acc;
                }
            }
            __syncthreads();
        }
        if (act) {
            long tb = (long)(tt * 8 + t_) * 25 + u_;
#pragma unroll
            for (int k = 0; k < 4; k++) {
                int o = o0 + grp * 4 + k;
                float yk = (k == 0) ? y0 : (k == 1) ? y1 : (k == 2) ? y2 : y3;
                y[((long)(n * 64 + o)) * 3200 + tb] = yk;
            }
        }
    }
}

// K4: per-channel sum / sumsq of y
__global__ void k_stats(const float* __restrict__ y, float* __restrict__ stats) {
    int o = blockIdx.x & 63, nc = blockIdx.x >> 6;   // 16 n-chunks
    float s = 0.f, s2 = 0.f;
    for (int nn = nc * 8; nn < nc * 8 + 8; nn++) {
        const float* p = y + (long)(nn * 64 + o) * 3200;
        for (int i = threadIdx.x; i < 3200; i += 256) {
            float v = p[i];
            s += v; s2 += v * v;
        }
    }
    for (int off = 32; off; off >>= 1) {
        s += __shfl_down(s, off);
        s2 += __shfl_down(s2, off);
    }
    __shared__ float rs[4], rs2[4];
    int w = threadIdx.x >> 6, lane = threadIdx.x & 63;
    if (lane == 0) { rs[w] = s; rs2[w] = s2; }
    __syncthreads();
    if (threadIdx.x == 0) {
        float a = 0.f, b = 0.f;
        for (int i = 0; i < 4; i++) { a += rs[i]; b += rs2[i]; }
        atomicAdd(&stats[o * 2], a);
        atomicAdd(&stats[o * 2 + 1], b);
    }
}

__global__ void k_coef(const float* __restrict__ stats, const float* __restrict__ bnw,
                       const float* __restrict__ bnb, float* __restrict__ coef) {
    int o = threadIdx.x;
    if (o < 64) {
        const float inv = 1.f / 409600.f;
        float mean = stats[o * 2] * inv;
        float var = stats[o * 2 + 1] * inv - mean * mean;
        float sc = bnw[o] * rsqrtf(var + 1e-5f);
        coef[o * 2] = sc;
        coef[o * 2 + 1] = bnb[o] - mean * sc;
    }
}

// K5: out = relu(y*scale + shift + x), in place on y (=d_out), float4
__global__ void k_final(float* __restrict__ y, const float* __restrict__ x,
                        const float* __restrict__ coef) {
    unsigned int i = blockIdx.x * 256u + threadIdx.x;   // 0..6,553,599 float4s
    unsigned int o = (i / 800u) & 63u;
    float sc = coef[o * 2], sh = coef[o * 2 + 1];
    float4 yv = ((const float4*)y)[i];
    float4 xv = ((const float4*)x)[i];
    float4 r;
    r.x = fmaxf(yv.x * sc + sh + xv.x, 0.f);
    r.y = fmaxf(yv.y * sc + sh + xv.y, 0.f);
    r.z = fmaxf(yv.z * sc + sh + xv.z, 0.f);
    r.w = fmaxf(yv.w * sc + sh + xv.w, 0.f);
    ((float4*)y)[i] = r;
}

extern "C" void kernel_launch(void* const* d_in, const int* in_sizes, int n_in,
                              void* d_out, int out_size, void* d_ws, size_t ws_size,
                              hipStream_t stream) {
    const float* x    = (const float*)d_in[0];
    const float* W1   = (const float*)d_in[1];
    const float* b1   = (const float*)d_in[2];
    const float* W2   = (const float*)d_in[3];
    const float* b2   = (const float*)d_in[4];
    const float* W3   = (const float*)d_in[5];
    const float* b3   = (const float*)d_in[6];
    const float* W4   = (const float*)d_in[7];
    const float* b4   = (const float*)d_in[8];
    const float* PA   = (const float*)d_in[9];
    const float* alpha= (const float*)d_in[10];
    const float* bnw  = (const float*)d_in[11];
    const float* bnb  = (const float*)d_in[12];

    float* ws     = (float*)d_ws;
    float* adj_ws = ws + ADJ_OFF;
    float* xbar   = ws + XBAR_OFF;
    float* stats  = ws + STATS_OFF;
    float* coef   = ws + COEF_OFF;
    float* y      = (float*)d_out;

    hipLaunchKernelGGL(k_zero, dim3(1), dim3(128), 0, stream, stats);
    hipLaunchKernelGGL(k_xbar, dim3(8192), dim3(64), 0, stream, x, xbar);
    hipLaunchKernelGGL(k_adj, dim3(384), dim3(256), 0, stream,
                       xbar, W1, b1, W2, b2, W4, b4, PA, alpha, adj_ws);
    hipLaunchKernelGGL(k_main, dim3(1024), dim3(512), 0, stream, x, W3, b3, adj_ws, y);
    hipLaunchKernelGGL(k_stats, dim3(1024), dim3(256), 0, stream, y, stats);
    hipLaunchKernelGGL(k_coef, dim3(1), dim3(64), 0, stream, stats, bnw, bnb, coef);
    hipLaunchKernelGGL(k_final, dim3(25600), dim3(256), 0, stream, y, x, coef);
}

// Round 2
// 220.144 us; speedup vs baseline: 4.0332x; 4.0332x over previous
//
#include <hip/hip_runtime.h>
#include <hip/hip_bf16.h>

// Shapes: N=128, C_IN=C_OUT=64, T=128, V=25, S=3, R=8
// ws layout (bytes):
//   adjfrag (bf16, B-frag-linear) [3][128][64][2 ut][64 lane][8 j] @ 0         50,331,648
//   w3frag  (bf16, B-frag-linear) [3][2 kb][4 ot][64 lane][8 j]    @ 50331648      24,576
//   xbar    (f32) [128][64][25]                                    @ 50356224     819,200
//   partials(f32) [64 o][2 stat][1024 blk]                         @ 51175424     524,288
//   stats   (f32) [128]                                            @ 51699712         512
//   coef    (f32) [64][2]                                          @ 51700224         512

typedef __attribute__((ext_vector_type(8))) short bf16x8;
typedef __attribute__((ext_vector_type(4))) float f32x4;

__device__ inline unsigned short f2bf(float f) {
    union { float f; unsigned int u; } x; x.f = f;
    unsigned int u = x.u;
    return (unsigned short)((u + 0x7FFFu + ((u >> 16) & 1u)) >> 16);
}

// ---- W3 -> B-fragment-linear bf16 ----
__global__ void k_w3prep(const float* __restrict__ W3, unsigned short* __restrict__ w3f) {
    int g = blockIdx.x * 512 + threadIdx.x;          // 0..1535
    if (g >= 1536) return;
    int grp = g >> 6, lane = g & 63;
    int s = grp >> 3, kb = (grp >> 2) & 1, ot = grp & 3;
    int o = ot * 16 + (lane & 15);
    int c0 = kb * 32 + (lane >> 4) * 8;
    const float* src = W3 + (s * 64 + o) * 64 + c0;
    unsigned int p[4];
#pragma unroll
    for (int e = 0; e < 4; e++)
        p[e] = (unsigned int)f2bf(src[2 * e]) | ((unsigned int)f2bf(src[2 * e + 1]) << 16);
    uint4 v; v.x = p[0]; v.y = p[1]; v.z = p[2]; v.w = p[3];
    *(uint4*)(w3f + (grp * 64 + lane) * 8) = v;
}

// ---- K1: xbar[n,c,v] = mean over t ----
__global__ void k_xbar(const float* __restrict__ x, float* __restrict__ xbar) {
    int nc = blockIdx.x;          // 0..8191
    int lane = threadIdx.x;       // 64
    const float* p = x + (long)nc * 3200;
    float acc[25];
#pragma unroll
    for (int v = 0; v < 25; v++) acc[v] = 0.f;
    for (int t = lane; t < 128; t += 64) {
        const float* q = p + t * 25;
#pragma unroll
        for (int v = 0; v < 25; v++) acc[v] += q[v];
    }
#pragma unroll
    for (int v = 0; v < 25; v++) {
        float a = acc[v];
        for (int off = 32; off; off >>= 1) a += __shfl_down(a, off);
        if (lane == 0) xbar[nc * 25 + v] = a * (1.f / 128.f);
    }
}

// ---- K2: adj in B-fragment-linear bf16, zero-padded for u>=25 / v>=25 ----
__global__ void k_adj(const float* __restrict__ xbar,
                      const float* __restrict__ W1, const float* __restrict__ b1,
                      const float* __restrict__ W2, const float* __restrict__ b2,
                      const float* __restrict__ W4, const float* __restrict__ b4,
                      const float* __restrict__ PA, const float* __restrict__ alpha,
                      unsigned short* __restrict__ adjfrag) {
    int sb = blockIdx.x;          // 0..383
    int s = sb >> 7, n = sb & 127;
    __shared__ float xb[1600], w1l[512], w2l[512], w4l[512], b4l[64], pal[625];
    __shared__ float x1l[200], x2l[200];
    __shared__ float dt[8][25][28];
    int tid = threadIdx.x;        // 256
    for (int i = tid; i < 1600; i += 256) xb[i] = xbar[n * 1600 + i];
    for (int i = tid; i < 512; i += 256) {
        w1l[i] = W1[s * 512 + i];
        w2l[i] = W2[s * 512 + i];
        w4l[i] = W4[s * 512 + i];
    }
    if (tid < 64) b4l[tid] = b4[s * 64 + tid];
    for (int i = tid; i < 625; i += 256) pal[i] = PA[s * 625 + i];
    __syncthreads();
    if (tid < 200) {
        int r = tid / 25, v = tid % 25;
        float a1 = b1[s * 8 + r], a2 = b2[s * 8 + r];
        for (int c = 0; c < 64; c++) {
            float xv = xb[c * 25 + v];
            a1 += w1l[r * 64 + c] * xv;
            a2 += w2l[r * 64 + c] * xv;
        }
        x1l[tid] = a1;
        x2l[tid] = a2;
    }
    __syncthreads();
    for (int i = tid; i < 5000; i += 256) {
        int r = i / 625, uv = i % 625, u = uv / 25, v = uv % 25;
        dt[r][u][v] = tanhf(x1l[r * 25 + u] - x2l[r * 25 + v]);
    }
    for (int i = tid; i < 600; i += 256) {          // zero pad cols 25..27
        int r = i / 75, rem = i % 75, u = rem / 3, v = 25 + rem % 3;
        dt[r][u][v] = 0.f;
    }
    __syncthreads();

    int f = tid * 4;                    // frag elem base within [0,1024)
    int lane = (f >> 3) & 63;
    int j0 = f & 7;                     // 0 or 4
    int u = ((f >> 9) << 4) + (lane & 15);
    int v0 = ((lane >> 4) << 3) + j0;   // 0..28 step 4
    bool uok = (u < 25);
    float4 dr[8];
    if (uok && v0 < 28) {
#pragma unroll
        for (int r = 0; r < 8; r++) dr[r] = *(const float4*)&dt[r][u][v0];
    } else {
#pragma unroll
        for (int r = 0; r < 8; r++) { dr[r].x = dr[r].y = dr[r].z = dr[r].w = 0.f; }
    }
    float al = alpha[s];
    bool vok[4]; float pae[4];
#pragma unroll
    for (int e = 0; e < 4; e++) {
        int v = v0 + e;
        vok[e] = uok && (v < 25);
        pae[e] = vok[e] ? pal[u * 25 + v] : 0.f;
    }
    unsigned short* outp = adjfrag + ((size_t)(s * 128 + n)) * 65536 + f;
    for (int o = 0; o < 64; o++) {
        float b4o = b4l[o];
        unsigned short q[4];
#pragma unroll
        for (int e = 0; e < 4; e++) {
            float acc = 0.f;
            if (vok[e]) {
                float dot = b4o;
                float de[4] = {dr[0].x, 0, 0, 0}; (void)de;
#pragma unroll
                for (int r = 0; r < 8; r++) {
                    float dv = (e == 0) ? dr[r].x : (e == 1) ? dr[r].y : (e == 2) ? dr[r].z : dr[r].w;
                    dot += w4l[o * 8 + r] * dv;
                }
                acc = dot * al + pae[e];
            }
            q[e] = f2bf(acc);
        }
        uint2 pk = make_uint2((unsigned int)q[0] | ((unsigned int)q[1] << 16),
                              (unsigned int)q[2] | ((unsigned int)q[3] << 16));
        *(uint2*)(outp + o * 1024) = pk;
    }
}

// ---- K3: MFMA main: x3 = W3.x + b3 ; y = sum_s adj . x3 ; BN partials ----
__launch_bounds__(512)
__global__ void k_main(const float* __restrict__ x, const float* __restrict__ b3g,
                       const unsigned short* __restrict__ w3f,
                       const unsigned short* __restrict__ adjf,
                       float* __restrict__ y, float* __restrict__ partials) {
    __shared__ unsigned short xl[32768];     // [m=512][c=64] bf16, XOR-swizzled
    __shared__ unsigned short x3l[20736];    // [o_loc=32][648]  (row = 16t x 40v, pad 8)
    __shared__ float b3l[192];

    int bid = blockIdx.x;                    // 0..1023
    int xcd = bid & 7, j = bid >> 3;
    int tt = j & 7, n = (xcd << 4) | (j >> 3);
    int tid = threadIdx.x;
    int w = tid >> 6, lane = tid & 63;
    int l15 = lane & 15, l4 = lane >> 4;

    // zero xl (pad rows v>=25 must be 0), load b3
    {
        unsigned long long* xz = (unsigned long long*)xl;
        for (int i = tid; i < 8192; i += 512) xz[i] = 0ULL;
        if (tid < 192) b3l[tid] = b3g[tid];
    }
    __syncthreads();

    // stage x chunk -> xl bf16 swizzled
    const float* xs = x + (size_t)n * 204800 + tt * 400;
    for (int idx = tid; idx < 6400; idx += 512) {
        int c = idx / 100, r4 = idx % 100;
        float4 q = *(const float4*)(xs + c * 3200 + r4 * 4);
        int tv = r4 * 4;
#pragma unroll
        for (int e = 0; e < 4; e++) {
            int t = (tv + e) / 25, v = (tv + e) % 25;
            int m = t * 32 + v;
            float val = (e == 0) ? q.x : (e == 1) ? q.y : (e == 2) ? q.z : q.w;
            xl[m * 64 + (c ^ ((m & 7) << 3))] = f2bf(val);
        }
    }
    __syncthreads();

    f32x4 zero4 = {0.f, 0.f, 0.f, 0.f};
    f32x4 yacc[16];
#pragma unroll
    for (int i = 0; i < 16; i++) yacc[i] = zero4;

    for (int s = 0; s < 3; s++) {
#pragma unroll
        for (int h = 0; h < 2; h++) {
            // ---- stage 1: x3 for o-half h ----
            {
                int ot2 = w & 1, mq = w >> 1;
                int ot = h * 2 + ot2;
                bf16x8 bf0 = *(const bf16x8*)(w3f + ((s * 8 + ot) * 64 + lane) * 8);
                bf16x8 bf1 = *(const bf16x8*)(w3f + ((s * 8 + 4 + ot) * 64 + lane) * 8);
                float bias = b3l[s * 64 + ot * 16 + l15];
                int o_loc = ot2 * 16 + l15;
#pragma unroll
                for (int mi = 0; mi < 8; mi++) {
                    int mt = mq * 8 + mi;
                    int m = mt * 16 + l15;
                    int sw = (m & 7) << 3;
                    bf16x8 a0 = *(const bf16x8*)(&xl[m * 64 + ((l4 * 8) ^ sw)]);
                    bf16x8 a1 = *(const bf16x8*)(&xl[m * 64 + ((32 + l4 * 8) ^ sw)]);
                    f32x4 d = zero4;
                    d = __builtin_amdgcn_mfma_f32_16x16x32_bf16(a0, bf0, d, 0, 0, 0);
                    d = __builtin_amdgcn_mfma_f32_16x16x32_bf16(a1, bf1, d, 0, 0, 0);
                    int t = mt >> 1, v0 = ((mt & 1) << 4) + l4 * 4;
                    unsigned int p0 = (unsigned int)f2bf(d[0] + bias) | ((unsigned int)f2bf(d[1] + bias) << 16);
                    unsigned int p1 = (unsigned int)f2bf(d[2] + bias) | ((unsigned int)f2bf(d[3] + bias) << 16);
                    *(uint2*)(&x3l[o_loc * 648 + t * 40 + v0]) = make_uint2(p0, p1);
                }
            }
            __syncthreads();
            // ---- stage 2: y += x3 . adjT ----
            {
                size_t abase = ((size_t)(s * 128 + n)) * 65536;
#pragma unroll
                for (int k = 0; k < 4; k++) {
                    int o_loc = (w << 2) + k;
                    int o = h * 32 + o_loc;
                    bf16x8 a = *(const bf16x8*)(&x3l[o_loc * 648 + l15 * 40 + l4 * 8]);
#pragma unroll
                    for (int ut = 0; ut < 2; ut++) {
                        bf16x8 b = *(const bf16x8*)(adjf + abase + ((size_t)o * 2 + ut) * 512 + lane * 8);
                        yacc[h * 8 + k * 2 + ut] =
                            __builtin_amdgcn_mfma_f32_16x16x32_bf16(a, b, yacc[h * 8 + k * 2 + ut], 0, 0, 0);
                    }
                }
            }
            __syncthreads();
        }
    }

    // ---- epilogue: y store + BN partials ----
#pragma unroll
    for (int h = 0; h < 2; h++) {
#pragma unroll
        for (int k = 0; k < 4; k++) {
            int o = h * 32 + (w << 2) + k;
            float s1 = 0.f, s2 = 0.f;
#pragma unroll
            for (int ut = 0; ut < 2; ut++) {
                f32x4 d = yacc[h * 8 + k * 2 + ut];
                int u = ut * 16 + l15;
#pragma unroll
                for (int r = 0; r < 4; r++) {
                    float val = d[r];
                    s1 += val; s2 += val * val;
                    if (u < 25) {
                        int tg = tt * 16 + l4 * 4 + r;
                        y[(((size_t)n * 64 + o) * 128 + tg) * 25 + u] = val;
                    }
                }
            }
#pragma unroll
            for (int off = 1; off < 64; off <<= 1) {
                s1 += __shfl_xor(s1, off);
                s2 += __shfl_xor(s2, off);
            }
            if (lane == 0) {
                partials[(o * 2 + 0) * 1024 + bid] = s1;
                partials[(o * 2 + 1) * 1024 + bid] = s2;
            }
        }
    }
}

// ---- K4: reduce partials ----
__global__ void k_reduce(const float* __restrict__ partials, float* __restrict__ stats) {
    int row = blockIdx.x;                    // 0..127
    float a = 0.f;
    for (int i = threadIdx.x; i < 1024; i += 256) a += partials[row * 1024 + i];
    for (int off = 32; off; off >>= 1) a += __shfl_down(a, off);
    __shared__ float r4[4];
    int wv = threadIdx.x >> 6, ln = threadIdx.x & 63;
    if (ln == 0) r4[wv] = a;
    __syncthreads();
    if (threadIdx.x == 0) stats[row] = r4[0] + r4[1] + r4[2] + r4[3];
}

__global__ void k_coef(const float* __restrict__ stats, const float* __restrict__ bnw,
                       const float* __restrict__ bnb, float* __restrict__ coef) {
    int o = threadIdx.x;
    if (o < 64) {
        const float inv = 1.f / 409600.f;
        float mean = stats[o * 2] * inv;
        float var = stats[o * 2 + 1] * inv - mean * mean;
        float sc = bnw[o] * rsqrtf(var + 1e-5f);
        coef[o * 2] = sc;
        coef[o * 2 + 1] = bnb[o] - mean * sc;
    }
}

// ---- K5: out = relu(y*scale + shift + x), in place on d_out ----
__global__ void k_final(float* __restrict__ y, const float* __restrict__ x,
                        const float* __restrict__ coef) {
    unsigned int i = blockIdx.x * 256u + threadIdx.x;
    unsigned int o = (i / 800u) & 63u;
    float sc = coef[o * 2], sh = coef[o * 2 + 1];
    float4 yv = ((const float4*)y)[i];
    float4 xv = ((const float4*)x)[i];
    float4 r;
    r.x = fmaxf(yv.x * sc + sh + xv.x, 0.f);
    r.y = fmaxf(yv.y * sc + sh + xv.y, 0.f);
    r.z = fmaxf(yv.z * sc + sh + xv.z, 0.f);
    r.w = fmaxf(yv.w * sc + sh + xv.w, 0.f);
    ((float4*)y)[i] = r;
}

extern "C" void kernel_launch(void* const* d_in, const int* in_sizes, int n_in,
                              void* d_out, int out_size, void* d_ws, size_t ws_size,
                              hipStream_t stream) {
    const float* x    = (const float*)d_in[0];
    const float* W1   = (const float*)d_in[1];
    const float* b1   = (const float*)d_in[2];
    const float* W2   = (const float*)d_in[3];
    const float* b2   = (const float*)d_in[4];
    const float* W3   = (const float*)d_in[5];
    const float* b3   = (const float*)d_in[6];
    const float* W4   = (const float*)d_in[7];
    const float* b4   = (const float*)d_in[8];
    const float* PA   = (const float*)d_in[9];
    const float* alpha= (const float*)d_in[10];
    const float* bnw  = (const float*)d_in[11];
    const float* bnb  = (const float*)d_in[12];

    char* wsb = (char*)d_ws;
    unsigned short* adjfrag = (unsigned short*)wsb;
    unsigned short* w3frag  = (unsigned short*)(wsb + 50331648);
    float* xbar     = (float*)(wsb + 50356224);
    float* partials = (float*)(wsb + 51175424);
    float* stats    = (float*)(wsb + 51699712);
    float* coef     = (float*)(wsb + 51700224);
    float* y        = (float*)d_out;

    hipLaunchKernelGGL(k_w3prep, dim3(3), dim3(512), 0, stream, W3, w3frag);
    hipLaunchKernelGGL(k_xbar, dim3(8192), dim3(64), 0, stream, x, xbar);
    hipLaunchKernelGGL(k_adj, dim3(384), dim3(256), 0, stream,
                       xbar, W1, b1, W2, b2, W4, b4, PA, alpha, adjfrag);
    hipLaunchKernelGGL(k_main, dim3(1024), dim3(512), 0, stream, x, b3, w3frag, adjfrag, y, partials);
    hipLaunchKernelGGL(k_reduce, dim3(128), dim3(256), 0, stream, partials, stats);
    hipLaunchKernelGGL(k_coef, dim3(1), dim3(64), 0, stream, stats, bnw, bnb, coef);
    hipLaunchKernelGGL(k_final, dim3(25600), dim3(256), 0, stream, y, x, coef);
}